// Round 1
// baseline (472.919 us; speedup 1.0000x reference)
//
#include <hip/hip_runtime.h>

// SpikeLoss: loss = 0.5 * sum((outputs - psp(target))^2)
// psp: syn_t = syn_{t-1}*(1-1/tau) + x_t ; out_t = syn_t/tau, along last axis T.
// Layout [B,C,H,W,T], T=100 contiguous. One thread per pixel (B*C*H*W = 524288).

constexpr int T  = 100;    // trailing axis length (fixed by setup_inputs)
constexpr int T4 = T / 4;  // float4 chunks per pixel (400 B, 16B-aligned rows)

__global__ __launch_bounds__(256) void spike_loss_kernel(
    const float4* __restrict__ outs,   // [pixels * T4]
    const float4* __restrict__ tgt,    // [pixels * T4]
    const int*    __restrict__ tau_p,  // scalar tau_s
    float*        __restrict__ out,    // [1], pre-zeroed
    int n_pixels)
{
    const float tau     = (float)tau_p[0];
    const float inv_tau = 1.0f / tau;
    const float decay   = 1.0f - inv_tau;

    const int pix = blockIdx.x * blockDim.x + threadIdx.x;
    float acc = 0.0f;

    if (pix < n_pixels) {
        const float4* tp = tgt  + (size_t)pix * T4;
        const float4* op = outs + (size_t)pix * T4;
        float syn = 0.0f;
        #pragma unroll 5
        for (int k = 0; k < T4; ++k) {
            const float4 t4 = tp[k];
            const float4 o4 = op[k];
            float d;
            syn = fmaf(syn, decay, t4.x); d = fmaf(-syn, inv_tau, o4.x); acc = fmaf(d, d, acc);
            syn = fmaf(syn, decay, t4.y); d = fmaf(-syn, inv_tau, o4.y); acc = fmaf(d, d, acc);
            syn = fmaf(syn, decay, t4.z); d = fmaf(-syn, inv_tau, o4.z); acc = fmaf(d, d, acc);
            syn = fmaf(syn, decay, t4.w); d = fmaf(-syn, inv_tau, o4.w); acc = fmaf(d, d, acc);
        }
    }

    // Wave-64 shuffle reduction
    #pragma unroll
    for (int off = 32; off > 0; off >>= 1)
        acc += __shfl_down(acc, off, 64);

    __shared__ float wave_sums[4];  // 256 threads = 4 waves
    const int lane = threadIdx.x & 63;
    const int wid  = threadIdx.x >> 6;
    if (lane == 0) wave_sums[wid] = acc;
    __syncthreads();

    if (threadIdx.x == 0) {
        const float s = wave_sums[0] + wave_sums[1] + wave_sums[2] + wave_sums[3];
        atomicAdd(out, 0.5f * s);
    }
}

extern "C" void kernel_launch(void* const* d_in, const int* in_sizes, int n_in,
                              void* d_out, int out_size, void* d_ws, size_t ws_size,
                              hipStream_t stream) {
    const float* outs = (const float*)d_in[0];   // outputs [B,C,H,W,T]
    const float* tgt  = (const float*)d_in[1];   // target  [B,C,H,W,T]
    // d_in[2] = n_steps (int, == T), d_in[3] = tau_s (int)
    const int* tau_p  = (const int*)d_in[3];
    float* out        = (float*)d_out;

    const int n_pixels = in_sizes[0] / T;        // 524288
    const int block = 256;
    const int grid  = (n_pixels + block - 1) / block;  // 2048

    // d_out is poisoned to 0xAA before every call — zero it (graph-capturable).
    hipMemsetAsync(out, 0, sizeof(float), stream);

    spike_loss_kernel<<<grid, block, 0, stream>>>(
        (const float4*)outs, (const float4*)tgt, tau_p, out, n_pixels);
}

// Round 2
// 415.883 us; speedup vs baseline: 1.1371x; 1.1371x over previous
//
#include <hip/hip_runtime.h>

// SpikeLoss: loss = 0.5 * sum((outputs - psp(target))^2)
// psp: syn_t = syn_{t-1}*decay + x_t ; psp_t = syn_t/tau, decay = 1 - 1/tau.
//
// Coalesced parallel-scan formulation:
//   - lanes 0..49 of each wave hold the 50 float4 chunks of 2 adjacent pixels
//     (contiguous 800 B per wave iteration -> perfect coalescing)
//   - 4-element inclusive scan in registers (carry factor decay per elem)
//   - inter-chunk carry: constant-coefficient Kogge-Stone over lanes with
//     factor a = decay^4 per chunk, masked at pixel boundaries (j = chunk
//     index within pixel). Steps d=1,2,4,8 cover >=9 chunks of history;
//     truncation error a^9 = 2^-36 (tau=2) -- far below fp32 eps.

constexpr int T   = 100;  // trailing axis length
constexpr int C4  = 25;   // float4 chunks per pixel
constexpr int LPW = 50;   // useful lanes per wave (2 pixels)

__global__ __launch_bounds__(256) void spike_loss_kernel(
    const float4* __restrict__ tgt4,
    const float4* __restrict__ outs4,
    const int*    __restrict__ tau_p,
    float*        __restrict__ out,     // [1], pre-zeroed
    int n_pairs)                        // n_pixels / 2
{
    const float tau     = (float)tau_p[0];
    const float inv_tau = 1.0f / tau;
    const float decay   = 1.0f - inv_tau;
    const float d2 = decay * decay;
    const float a1 = d2 * d2;      // decay^4 : carry factor per chunk
    const float a2 = a1 * a1;
    const float a4 = a2 * a2;
    const float a8 = a4 * a4;

    const int lane    = threadIdx.x & 63;
    const int wave_id = (blockIdx.x * blockDim.x + threadIdx.x) >> 6;
    const int n_waves = (gridDim.x * blockDim.x) >> 6;
    const int j       = (lane < C4) ? lane : lane - C4;  // chunk idx in pixel
    const bool active = lane < LPW;

    float acc = 0.0f;

    #pragma unroll 2
    for (int pp = wave_id; pp < n_pairs; pp += n_waves) {
        const size_t base = (size_t)pp * LPW + lane;
        float4 t4, o4;
        if (active) {
            t4 = tgt4[base];
            o4 = outs4[base];
        } else {
            t4 = make_float4(0.f, 0.f, 0.f, 0.f);
            o4 = make_float4(0.f, 0.f, 0.f, 0.f);
        }

        // local inclusive scan over the 4 elements (syn_in = 0)
        float s1 = fmaf(t4.x, decay, t4.y);
        float s2 = fmaf(s1,  decay, t4.z);
        float s3 = fmaf(s2,  decay, t4.w);

        // Kogge-Stone constant-coefficient scan across chunk lanes:
        // X_l = s3_l + a * X_{l-1}  (within pixel segment)
        float X = s3;
        float y;
        y = __shfl_up(X, 1, 64); if (j >= 1) X = fmaf(y, a1, X);
        y = __shfl_up(X, 2, 64); if (j >= 2) X = fmaf(y, a2, X);
        y = __shfl_up(X, 4, 64); if (j >= 4) X = fmaf(y, a4, X);
        y = __shfl_up(X, 8, 64); if (j >= 8) X = fmaf(y, a8, X);

        // carry into this chunk = syn at end of previous chunk
        float cin = __shfl_up(X, 1, 64);
        if (j == 0) cin = 0.0f;

        if (active) {
            float syn = cin, d;
            syn = fmaf(syn, decay, t4.x); d = fmaf(syn, -inv_tau, o4.x); acc = fmaf(d, d, acc);
            syn = fmaf(syn, decay, t4.y); d = fmaf(syn, -inv_tau, o4.y); acc = fmaf(d, d, acc);
            syn = fmaf(syn, decay, t4.z); d = fmaf(syn, -inv_tau, o4.z); acc = fmaf(d, d, acc);
            syn = fmaf(syn, decay, t4.w); d = fmaf(syn, -inv_tau, o4.w); acc = fmaf(d, d, acc);
        }
    }

    // wave-64 shuffle reduction
    #pragma unroll
    for (int off = 32; off > 0; off >>= 1)
        acc += __shfl_down(acc, off, 64);

    __shared__ float wave_sums[4];
    const int wid = threadIdx.x >> 6;
    if (lane == 0) wave_sums[wid] = acc;
    __syncthreads();

    if (threadIdx.x == 0) {
        const float s = wave_sums[0] + wave_sums[1] + wave_sums[2] + wave_sums[3];
        atomicAdd(out, 0.5f * s);
    }
}

extern "C" void kernel_launch(void* const* d_in, const int* in_sizes, int n_in,
                              void* d_out, int out_size, void* d_ws, size_t ws_size,
                              hipStream_t stream) {
    const float* outs = (const float*)d_in[0];   // outputs [B,C,H,W,T]
    const float* tgt  = (const float*)d_in[1];   // target  [B,C,H,W,T]
    const int* tau_p  = (const int*)d_in[3];     // tau_s
    float* out        = (float*)d_out;

    const int n_pixels = in_sizes[0] / T;        // 524288
    const int n_pairs  = n_pixels / 2;           // 262144

    const int block = 256;
    const int grid  = 2048;   // 8192 waves -> 32 pixel-pairs each, 32 waves/CU

    // d_out is poisoned to 0xAA before every call — zero it (graph-capturable).
    hipMemsetAsync(out, 0, sizeof(float), stream);

    spike_loss_kernel<<<grid, block, 0, stream>>>(
        (const float4*)tgt, (const float4*)outs, tau_p, out, n_pairs);
}

// Round 3
// 410.057 us; speedup vs baseline: 1.1533x; 1.0142x over previous
//
#include <hip/hip_runtime.h>

// SpikeLoss: loss = 0.5 * sum((outputs - psp(target))^2)
// psp: syn_t = syn_{t-1}*decay + x_t ; psp_t = syn_t/tau, decay = 1 - 1/tau.
//
// Coalesced parallel-scan + deep-unroll formulation:
//   - lanes 0..49 of each wave hold the 50 float4 chunks of 2 adjacent pixels
//     (contiguous 800 B per load instruction -> perfect coalescing)
//   - U=4 pair-steps per iteration, ALL 8 loads issued before any processing
//     (8 independent vmem ops in flight per wave -> latency hiding)
//   - 4-element inclusive scan in registers, inter-chunk carry via masked
//     Kogge-Stone over lanes with factor a = decay^4 (tau=2 -> a=1/16;
//     truncation at 9 chunks of history = 16^-9, far below fp32 eps)
//   - inactive lanes (50..63) load clamped addresses (no OOB) and are masked
//     out of the accumulator; shfl_up only reads lower lanes so their garbage
//     never reaches active lanes.

constexpr int T   = 100;  // trailing axis length
constexpr int C4  = 25;   // float4 chunks per pixel
constexpr int LPW = 50;   // useful lanes per wave (2 pixels)
constexpr int U   = 4;    // pair-steps unrolled per loop iteration

__global__ __launch_bounds__(256) void spike_loss_kernel(
    const float4* __restrict__ tgt4,
    const float4* __restrict__ outs4,
    const int*    __restrict__ tau_p,
    float*        __restrict__ out,     // [1], pre-zeroed
    int n_pairs)                        // n_pixels / 2 (divisible by n_waves*U)
{
    const float tau     = (float)tau_p[0];
    const float inv_tau = 1.0f / tau;
    const float decay   = 1.0f - inv_tau;
    const float d2 = decay * decay;
    const float a1 = d2 * d2;      // decay^4 : carry factor per chunk
    const float a2 = a1 * a1;
    const float a4 = a2 * a2;
    const float a8 = a4 * a4;

    const int lane    = threadIdx.x & 63;
    const int wave_id = (blockIdx.x * blockDim.x + threadIdx.x) >> 6;
    const int n_waves = (gridDim.x * blockDim.x) >> 6;
    const int j       = (lane < C4) ? lane : lane - C4;  // chunk idx in pixel
    const bool active = lane < LPW;

    const size_t last_chunk = (size_t)n_pairs * LPW - 1;  // clamp for lanes>=50

    float acc = 0.0f;

    for (int pp = wave_id * U; pp < n_pairs; pp += n_waves * U) {
        float4 t[U], o[U];
        // ---- issue all loads first: 2*U independent vmem ops in flight ----
        #pragma unroll
        for (int u = 0; u < U; ++u) {
            size_t base = (size_t)(pp + u) * LPW + lane;
            base = base < last_chunk ? base : last_chunk;
            t[u] = tgt4[base];
            o[u] = outs4[base];
        }
        // ---- process ----
        #pragma unroll
        for (int u = 0; u < U; ++u) {
            const float4 t4 = t[u];
            const float4 o4 = o[u];

            // local inclusive scan over the 4 elements (syn_in = 0)
            float s1 = fmaf(t4.x, decay, t4.y);
            float s2 = fmaf(s1,  decay, t4.z);
            float s3 = fmaf(s2,  decay, t4.w);

            // Kogge-Stone constant-coefficient scan across chunk lanes
            float X = s3;
            float y;
            y = __shfl_up(X, 1, 64); if (j >= 1) X = fmaf(y, a1, X);
            y = __shfl_up(X, 2, 64); if (j >= 2) X = fmaf(y, a2, X);
            y = __shfl_up(X, 4, 64); if (j >= 4) X = fmaf(y, a4, X);
            y = __shfl_up(X, 8, 64); if (j >= 8) X = fmaf(y, a8, X);

            // carry into this chunk = syn at end of previous chunk
            float cin = __shfl_up(X, 1, 64);
            if (j == 0) cin = 0.0f;

            if (active) {
                float syn = cin, d;
                syn = fmaf(syn, decay, t4.x); d = fmaf(syn, -inv_tau, o4.x); acc = fmaf(d, d, acc);
                syn = fmaf(syn, decay, t4.y); d = fmaf(syn, -inv_tau, o4.y); acc = fmaf(d, d, acc);
                syn = fmaf(syn, decay, t4.z); d = fmaf(syn, -inv_tau, o4.z); acc = fmaf(d, d, acc);
                syn = fmaf(syn, decay, t4.w); d = fmaf(syn, -inv_tau, o4.w); acc = fmaf(d, d, acc);
            }
        }
    }

    // wave-64 shuffle reduction
    #pragma unroll
    for (int off = 32; off > 0; off >>= 1)
        acc += __shfl_down(acc, off, 64);

    __shared__ float wave_sums[4];
    const int wid = threadIdx.x >> 6;
    if (lane == 0) wave_sums[wid] = acc;
    __syncthreads();

    if (threadIdx.x == 0) {
        const float s = wave_sums[0] + wave_sums[1] + wave_sums[2] + wave_sums[3];
        atomicAdd(out, 0.5f * s);
    }
}

extern "C" void kernel_launch(void* const* d_in, const int* in_sizes, int n_in,
                              void* d_out, int out_size, void* d_ws, size_t ws_size,
                              hipStream_t stream) {
    const float* outs = (const float*)d_in[0];   // outputs [B,C,H,W,T]
    const float* tgt  = (const float*)d_in[1];   // target  [B,C,H,W,T]
    const int* tau_p  = (const int*)d_in[3];     // tau_s
    float* out        = (float*)d_out;

    const int n_pixels = in_sizes[0] / T;        // 524288
    const int n_pairs  = n_pixels / 2;           // 262144

    const int block = 256;
    const int grid  = 2048;   // 8192 waves -> 32 pairs each = 8 U=4 steps

    // d_out is poisoned to 0xAA before every call — zero it (graph-capturable).
    hipMemsetAsync(out, 0, sizeof(float), stream);

    spike_loss_kernel<<<grid, block, 0, stream>>>(
        (const float4*)tgt, (const float4*)outs, tau_p, out, n_pairs);
}

// Round 4
// 396.311 us; speedup vs baseline: 1.1933x; 1.0347x over previous
//
#include <hip/hip_runtime.h>

// SpikeLoss: loss = 0.5 * sum((outputs - psp(target))^2)
// psp: syn_t = syn_{t-1}*decay + x_t ; psp_t = syn_t/tau, decay = 1 - 1/tau.
//
// R4: global_load_lds DMA streaming to break the per-CU outstanding-load cap.
//  - 128-thread blocks (2 waves), 32-pixel tiles (12.8 KB per array)
//  - both arrays DMA'd to LDS, double-buffered (51.2 KB/block, 3 blocks/CU)
//  - contiguous per-block tile slabs (better DRAM locality than grid-stride)
//  - processing: thread (p = tid>>2, q = tid&3) scans a 25-elem segment of
//    pixel p from LDS with zero carry-in; true carry combined from the
//    pixel's other segments via __shfl_up with weights decay^25k
//    (tau=2 -> 2^-25: below fp32 eps relative, exact in effect)
//  - pipeline per tile: s_waitcnt vmcnt(0); barrier; issue next tile DMA;
//    process current tile.

constexpr int T    = 100;   // trailing axis length
constexpr int SEG  = 25;    // elements per thread-segment
constexpr int PIX  = 32;    // pixels per tile
constexpr int TF   = PIX * T;          // 3200 floats = 12.8 KB per array
constexpr int FULL = (TF * 4) / 1024;  // 12 full 1-KB DMA chunks (3072 floats)

typedef const __attribute__((address_space(1))) void* gas_t;
typedef __attribute__((address_space(3))) void*       las_t;

__global__ __launch_bounds__(128) void spike_loss_kernel(
    const float* __restrict__ tgt,
    const float* __restrict__ outs,
    const int*   __restrict__ tau_p,
    float*       __restrict__ out,     // [1], pre-zeroed
    int n_tiles, int tiles_per_block)
{
    __shared__ float lds_t[2][TF];
    __shared__ float lds_o[2][TF];
    __shared__ float ws[2];

    const float tau     = (float)tau_p[0];
    const float inv_tau = 1.0f / tau;
    const float decay   = 1.0f - inv_tau;
    float d25 = 1.0f;
    #pragma unroll
    for (int i = 0; i < SEG; ++i) d25 *= decay;   // decay^25
    const float d50 = d25 * d25;

    const int lane = threadIdx.x & 63;
    const int wv   = threadIdx.x >> 6;            // 0..1

    const int first = blockIdx.x * tiles_per_block;
    int cnt = n_tiles - first;
    if (cnt < 0) cnt = 0;
    if (cnt > tiles_per_block) cnt = tiles_per_block;

    float acc = 0.0f;

    // ---- DMA stage: each wave issues 12 w16 + 2 w4 per array ----
    auto stage = [&](int tile, int buf) {
        const float* gt = tgt  + (size_t)tile * TF;
        const float* go = outs + (size_t)tile * TF;
        #pragma unroll
        for (int i = 0; i < FULL / 2; ++i) {
            const int c   = i * 2 + wv;          // chunk 0..11
            const int off = c * 256 + lane * 4;  // floats
            __builtin_amdgcn_global_load_lds((gas_t)(gt + off),
                (las_t)&lds_t[buf][c * 256], 16, 0, 0);
            __builtin_amdgcn_global_load_lds((gas_t)(go + off),
                (las_t)&lds_o[buf][c * 256], 16, 0, 0);
        }
        {   // 512-B tail: floats [3072, 3200) as two width-4 DMAs
            const int off = FULL * 256 + wv * 64 + lane;
            __builtin_amdgcn_global_load_lds((gas_t)(gt + off),
                (las_t)&lds_t[buf][FULL * 256 + wv * 64], 4, 0, 0);
            __builtin_amdgcn_global_load_lds((gas_t)(go + off),
                (las_t)&lds_o[buf][FULL * 256 + wv * 64], 4, 0, 0);
        }
    };

    auto process = [&](int buf) {
        const int p    = threadIdx.x >> 2;   // pixel in tile, 0..31
        const int q    = threadIdx.x & 3;    // segment in pixel
        const int base = p * T + q * SEG;

        float s[SEG];
        float syn = 0.0f;
        #pragma unroll
        for (int i = 0; i < SEG; ++i) {
            syn = fmaf(syn, decay, lds_t[buf][base + i]);
            s[i] = syn;
        }
        // carry into segment q = syn at end of segment q-1 (true value):
        // S_{q-1} = E_{q-1} + d25*E_{q-2} + d50*E_{q-3}
        const float f1 = __shfl_up(syn, 1, 64);
        const float f2 = __shfl_up(syn, 2, 64);
        const float f3 = __shfl_up(syn, 3, 64);
        float carry = (q >= 1) ? f1 : 0.0f;
        if (q >= 2) carry = fmaf(f2, d25, carry);
        if (q >= 3) carry = fmaf(f3, d50, carry);

        float cp = carry;
        #pragma unroll
        for (int i = 0; i < SEG; ++i) {
            cp *= decay;                       // carry*decay^{i+1}
            const float st = s[i] + cp;        // true syn
            const float d  = fmaf(st, -inv_tau, lds_o[buf][base + i]);
            acc = fmaf(d, d, acc);
        }
    };

    if (cnt > 0) stage(first, 0);

    for (int k = 0; k < cnt; ++k) {
        // drain this wave's DMAs (tile k's loads), then block-wide barrier so
        // every wave's share of tile k is visible in LDS.
        asm volatile("s_waitcnt vmcnt(0)" ::: "memory");
        __syncthreads();
        if (k + 1 < cnt) stage(first + k + 1, (k + 1) & 1);
        process(k & 1);
    }

    // ---- reduction ----
    #pragma unroll
    for (int off = 32; off > 0; off >>= 1)
        acc += __shfl_down(acc, off, 64);
    if (lane == 0) ws[wv] = acc;
    __syncthreads();
    if (threadIdx.x == 0)
        atomicAdd(out, 0.5f * (ws[0] + ws[1]));
}

extern "C" void kernel_launch(void* const* d_in, const int* in_sizes, int n_in,
                              void* d_out, int out_size, void* d_ws, size_t ws_size,
                              hipStream_t stream) {
    const float* outs = (const float*)d_in[0];   // outputs [B,C,H,W,T]
    const float* tgt  = (const float*)d_in[1];   // target  [B,C,H,W,T]
    const int* tau_p  = (const int*)d_in[3];     // tau_s
    float* out        = (float*)d_out;

    const int n_pixels = in_sizes[0] / T;        // 524288
    const int n_tiles  = n_pixels / PIX;         // 16384

    const int block = 128;
    const int grid  = 768;                       // 3 blocks/CU (LDS-bound)
    const int tiles_per_block = (n_tiles + grid - 1) / grid;  // 22

    // d_out is poisoned to 0xAA before every call — zero it (graph-capturable).
    hipMemsetAsync(out, 0, sizeof(float), stream);

    spike_loss_kernel<<<grid, block, 0, stream>>>(
        tgt, outs, tau_p, out, n_tiles, tiles_per_block);
}